// Round 1
// baseline (2775.288 us; speedup 1.0000x reference)
//
#include <hip/hip_runtime.h>
#include <math.h>

#define HEADS 4
#define HD 32
#define DIM 128
#define NEG_SLOPE 0.2f
#define EPS_SM 1e-8f
#define EPS_LN 1e-5f

__device__ __forceinline__ unsigned f2ord(float f) {
    unsigned b = __float_as_uint(f);
    return (b & 0x80000000u) ? ~b : (b | 0x80000000u);
}
__device__ __forceinline__ float ord2f(unsigned u) {
    unsigned b = (u & 0x80000000u) ? (u & 0x7fffffffu) : ~u;
    return __uint_as_float(b);
}
__device__ __forceinline__ float lrelu(float x) { return x > 0.f ? x : NEG_SLOPE * x; }

// ---------------- GEMM: out[N,128] = h[N,128] @ W[128,128] ----------------
__global__ __launch_bounds__(256) void gemm_k(const float* __restrict__ h,
                                              const float* __restrict__ W,
                                              float* __restrict__ out, int N) {
    __shared__ float hs[16][DIM];
    const int row0 = blockIdx.x * 16;
    const int tid = threadIdx.x;
    // load 16x128 tile as float4 (2048 floats = 512 float4 / 256 threads = 2 each)
    for (int i = tid; i < 512; i += 256) {
        int r = i >> 5, c4 = i & 31;
        int gr = row0 + r;
        float4 v = make_float4(0.f, 0.f, 0.f, 0.f);
        if (gr < N) v = ((const float4*)h)[gr * 32 + c4];
        ((float4*)&hs[r][0])[c4] = v;
    }
    __syncthreads();
    const int col = tid & 127;
    const int rbase = (tid >> 7) * 8;  // 0 or 8
    float acc[8] = {0.f, 0.f, 0.f, 0.f, 0.f, 0.f, 0.f, 0.f};
#pragma unroll 8
    for (int k = 0; k < DIM; ++k) {
        float w = W[k * DIM + col];
#pragma unroll
        for (int r = 0; r < 8; ++r) acc[r] += hs[rbase + r][k] * w;
    }
    for (int r = 0; r < 8; ++r) {
        int gr = row0 + rbase + r;
        if (gr < N) out[gr * DIM + col] = acc[r];
    }
}

// ------------- per-node per-head attention scalars (4 tables, N*4) -------------
__global__ __launch_bounds__(256) void node_dots_k(const float* __restrict__ hp,
                                                   const float* __restrict__ a_in,
                                                   const float* __restrict__ a_out,
                                                   float* __restrict__ pA0, float* __restrict__ pA1,
                                                   float* __restrict__ pB0, float* __restrict__ pB1,
                                                   int N) {
    int idx = blockIdx.x * 256 + threadIdx.x;  // n*4 + h
    if (idx >= N * HEADS) return;
    int n = idx >> 2, hh = idx & 3;
    const float4* v4 = (const float4*)(hp + (size_t)n * DIM + hh * HD);
    const float4* ai = (const float4*)(a_in + hh * 2 * HD);
    const float4* ao = (const float4*)(a_out + hh * 2 * HD);
    float s0 = 0.f, s1 = 0.f, s2 = 0.f, s3 = 0.f;
#pragma unroll
    for (int i = 0; i < 8; ++i) {
        float4 v = v4[i];
        float4 x0 = ai[i], x1 = ai[8 + i], y0 = ao[i], y1 = ao[8 + i];
        s0 += v.x * x0.x + v.y * x0.y + v.z * x0.z + v.w * x0.w;
        s1 += v.x * x1.x + v.y * x1.y + v.z * x1.z + v.w * x1.w;
        s2 += v.x * y0.x + v.y * y0.y + v.z * y0.z + v.w * y0.w;
        s3 += v.x * y1.x + v.y * y1.y + v.z * y1.z + v.w * y1.w;
    }
    pA0[idx] = s0; pA1[idx] = s1; pB0[idx] = s2; pB1[idx] = s3;
}

__global__ __launch_bounds__(256) void init_max_k(unsigned* __restrict__ p, int n) {
    int i = blockIdx.x * 256 + threadIdx.x;
    if (i < n) p[i] = 0x007FFFFFu;  // f2ord(-inf)
}

// ------------- edge pass 1: per-receiver max of leakyrelu(e) -------------
__global__ __launch_bounds__(256) void edge_max_k(const int* __restrict__ ei,
                                                  const float* __restrict__ pA0, const float* __restrict__ pA1,
                                                  const float* __restrict__ pB0, const float* __restrict__ pB1,
                                                  unsigned* __restrict__ max_in, unsigned* __restrict__ max_out,
                                                  int E) {
    int e = blockIdx.x * 256 + threadIdx.x;
    if (e >= E) return;
    int s = ei[e], d = ei[E + e];
    float4 a0 = ((const float4*)pA0)[s];
    float4 a1 = ((const float4*)pA1)[d];
    float4 b0 = ((const float4*)pB0)[d];
    float4 b1 = ((const float4*)pB1)[s];
    float ein[4] = {lrelu(a0.x + a1.x), lrelu(a0.y + a1.y), lrelu(a0.z + a1.z), lrelu(a0.w + a1.w)};
    float eout[4] = {lrelu(b0.x + b1.x), lrelu(b0.y + b1.y), lrelu(b0.z + b1.z), lrelu(b0.w + b1.w)};
#pragma unroll
    for (int hh = 0; hh < 4; ++hh) {
        atomicMax(&max_in[d * 4 + hh], f2ord(ein[hh]));
        atomicMax(&max_out[s * 4 + hh], f2ord(eout[hh]));
    }
}

// ------------- edge pass 2: alpha sums -------------
__global__ __launch_bounds__(256) void edge_sum_k(const int* __restrict__ ei,
                                                  const float* __restrict__ pA0, const float* __restrict__ pA1,
                                                  const float* __restrict__ pB0, const float* __restrict__ pB1,
                                                  const unsigned* __restrict__ max_in, const unsigned* __restrict__ max_out,
                                                  float* __restrict__ sum_in, float* __restrict__ sum_out,
                                                  int E) {
    int e = blockIdx.x * 256 + threadIdx.x;
    if (e >= E) return;
    int s = ei[e], d = ei[E + e];
    float4 a0 = ((const float4*)pA0)[s];
    float4 a1 = ((const float4*)pA1)[d];
    float4 b0 = ((const float4*)pB0)[d];
    float4 b1 = ((const float4*)pB1)[s];
    float ein[4] = {lrelu(a0.x + a1.x), lrelu(a0.y + a1.y), lrelu(a0.z + a1.z), lrelu(a0.w + a1.w)};
    float eout[4] = {lrelu(b0.x + b1.x), lrelu(b0.y + b1.y), lrelu(b0.z + b1.z), lrelu(b0.w + b1.w)};
#pragma unroll
    for (int hh = 0; hh < 4; ++hh) {
        atomicAdd(&sum_in[d * 4 + hh], expf(ein[hh] - ord2f(max_in[d * 4 + hh])));
        atomicAdd(&sum_out[s * 4 + hh], expf(eout[hh] - ord2f(max_out[s * 4 + hh])));
    }
}

// ------------- edge pass 3: weighted aggregation (both directions) -------------
__global__ __launch_bounds__(256) void edge_aggr_k(const int* __restrict__ ei,
                                                   const float* __restrict__ hp,
                                                   const float* __restrict__ pA0, const float* __restrict__ pA1,
                                                   const float* __restrict__ pB0, const float* __restrict__ pB1,
                                                   const unsigned* __restrict__ max_in, const unsigned* __restrict__ max_out,
                                                   const float* __restrict__ sum_in, const float* __restrict__ sum_out,
                                                   float* __restrict__ hacc_in, float* __restrict__ hacc_out,
                                                   int E) {
    long long idx = (long long)blockIdx.x * 256 + threadIdx.x;
    if (idx >= (long long)E * DIM) return;
    int e = (int)(idx >> 7);
    int c = (int)(idx & 127);
    int hh = c >> 5;
    int s = ei[e], d = ei[E + e];
    // in-direction: sender=s, receiver=d
    float ein = lrelu(pA0[s * 4 + hh] + pA1[d * 4 + hh]);
    float win = expf(ein - ord2f(max_in[d * 4 + hh])) / (sum_in[d * 4 + hh] + EPS_SM);
    atomicAdd(&hacc_in[(size_t)d * DIM + c], hp[(size_t)s * DIM + c] * win);
    // out-direction: sender=d, receiver=s
    float eout = lrelu(pB0[d * 4 + hh] + pB1[s * 4 + hh]);
    float wout = expf(eout - ord2f(max_out[s * 4 + hh])) / (sum_out[s * 4 + hh] + EPS_SM);
    atomicAdd(&hacc_out[(size_t)s * DIM + c], hp[(size_t)d * DIM + c] * wout);
}

// ------------- final: combine + LayerNorm (one wave per node) -------------
__global__ __launch_bounds__(256) void final_ln_k(const float* __restrict__ h_self,
                                                  const float* __restrict__ hacc_in,
                                                  const float* __restrict__ hacc_out,
                                                  const float* __restrict__ bias,
                                                  const float* __restrict__ gamma,
                                                  const float* __restrict__ beta,
                                                  float* __restrict__ out, int N) {
    int wave = threadIdx.x >> 6;
    int lane = threadIdx.x & 63;
    int n = blockIdx.x * 4 + wave;
    if (n >= N) return;
    size_t base = (size_t)n * DIM;
    int c0 = lane, c1 = lane + 64;
    float x0 = h_self[base + c0] + hacc_in[base + c0] + hacc_out[base + c0] + bias[c0];
    float x1 = h_self[base + c1] + hacc_in[base + c1] + hacc_out[base + c1] + bias[c1];
    float sum = x0 + x1, sq = x0 * x0 + x1 * x1;
#pragma unroll
    for (int m = 1; m < 64; m <<= 1) {
        sum += __shfl_xor(sum, m, 64);
        sq += __shfl_xor(sq, m, 64);
    }
    float mean = sum * (1.f / 128.f);
    float var = sq * (1.f / 128.f) - mean * mean;
    float inv = rsqrtf(var + EPS_LN);
    out[base + c0] = (x0 - mean) * inv * gamma[c0] + beta[c0];
    out[base + c1] = (x1 - mean) * inv * gamma[c1] + beta[c1];
}

extern "C" void kernel_launch(void* const* d_in, const int* in_sizes, int n_in,
                              void* d_out, int out_size, void* d_ws, size_t ws_size,
                              hipStream_t stream) {
    const float* h      = (const float*)d_in[0];
    const int*   ei     = (const int*)d_in[1];
    const float* W      = (const float*)d_in[2];
    const float* W_self = (const float*)d_in[3];
    const float* a_in   = (const float*)d_in[4];
    const float* a_out  = (const float*)d_in[5];
    const float* bias   = (const float*)d_in[6];
    const float* gamma  = (const float*)d_in[7];
    const float* beta   = (const float*)d_in[8];
    float* out = (float*)d_out;

    const int N = in_sizes[0] / DIM;
    const int E = in_sizes[1] / 2;

    // workspace layout (floats)
    float* ws = (float*)d_ws;
    size_t off = 0;
    float* h_proj = ws + off; off += (size_t)N * DIM;
    float* h_self = ws + off; off += (size_t)N * DIM;
    float* pA0 = ws + off; off += (size_t)N * 4;
    float* pA1 = ws + off; off += (size_t)N * 4;
    float* pB0 = ws + off; off += (size_t)N * 4;
    float* pB1 = ws + off; off += (size_t)N * 4;
    unsigned* max_in  = (unsigned*)(ws + off); off += (size_t)N * 4;
    unsigned* max_out = (unsigned*)(ws + off); off += (size_t)N * 4;
    // contiguous zero region: sum_in, sum_out, hacc_in, hacc_out
    float* zero_base = ws + off;
    float* sum_in  = ws + off; off += (size_t)N * 4;
    float* sum_out = ws + off; off += (size_t)N * 4;
    float* hacc_in  = ws + off; off += (size_t)N * DIM;
    float* hacc_out = ws + off; off += (size_t)N * DIM;
    size_t zero_bytes = (size_t)(N * 4 * 2 + N * DIM * 2) * sizeof(float);

    hipMemsetAsync(zero_base, 0, zero_bytes, stream);
    init_max_k<<<(N * 4 * 2 + 255) / 256, 256, 0, stream>>>(max_in, N * 4 * 2);

    int gblocks = (N + 15) / 16;
    gemm_k<<<gblocks, 256, 0, stream>>>(h, W, h_proj, N);
    gemm_k<<<gblocks, 256, 0, stream>>>(h, W_self, h_self, N);

    node_dots_k<<<(N * 4 + 255) / 256, 256, 0, stream>>>(h_proj, a_in, a_out, pA0, pA1, pB0, pB1, N);

    int eblocks = (E + 255) / 256;
    edge_max_k<<<eblocks, 256, 0, stream>>>(ei, pA0, pA1, pB0, pB1, max_in, max_out, E);
    edge_sum_k<<<eblocks, 256, 0, stream>>>(ei, pA0, pA1, pB0, pB1, max_in, max_out, sum_in, sum_out, E);

    long long total = (long long)E * DIM;
    int ablocks = (int)((total + 255) / 256);
    edge_aggr_k<<<ablocks, 256, 0, stream>>>(ei, h_proj, pA0, pA1, pB0, pB1,
                                             max_in, max_out, sum_in, sum_out,
                                             hacc_in, hacc_out, E);

    final_ln_k<<<(N + 3) / 4, 256, 0, stream>>>(h_self, hacc_in, hacc_out, bias, gamma, beta, out, N);
}

// Round 2
// 1001.795 us; speedup vs baseline: 2.7703x; 2.7703x over previous
//
#include <hip/hip_runtime.h>
#include <math.h>

#define HEADS 4
#define HD 32
#define DIM 128
#define NEG_SLOPE 0.2f
#define EPS_SM 1e-8f
#define EPS_LN 1e-5f

__device__ __forceinline__ float lrelu(float x) { return x > 0.f ? x : NEG_SLOPE * x; }

// ---------------- GEMM: out[N,128] = h[N,128] @ W[128,128] ----------------
__global__ __launch_bounds__(256) void gemm_k(const float* __restrict__ h,
                                              const float* __restrict__ W,
                                              float* __restrict__ out, int N) {
    __shared__ float hs[16][DIM];
    const int row0 = blockIdx.x * 16;
    const int tid = threadIdx.x;
    for (int i = tid; i < 512; i += 256) {
        int r = i >> 5, c4 = i & 31;
        int gr = row0 + r;
        float4 v = make_float4(0.f, 0.f, 0.f, 0.f);
        if (gr < N) v = ((const float4*)h)[gr * 32 + c4];
        ((float4*)&hs[r][0])[c4] = v;
    }
    __syncthreads();
    const int col = tid & 127;
    const int rbase = (tid >> 7) * 8;
    float acc[8] = {0.f, 0.f, 0.f, 0.f, 0.f, 0.f, 0.f, 0.f};
#pragma unroll 8
    for (int k = 0; k < DIM; ++k) {
        float w = W[k * DIM + col];
#pragma unroll
        for (int r = 0; r < 8; ++r) acc[r] += hs[rbase + r][k] * w;
    }
    for (int r = 0; r < 8; ++r) {
        int gr = row0 + rbase + r;
        if (gr < N) out[gr * DIM + col] = acc[r];
    }
}

// ------------- per-node per-head attention scalars (4 tables, N*4) -------------
__global__ __launch_bounds__(256) void node_dots_k(const float* __restrict__ hp,
                                                   const float* __restrict__ a_in,
                                                   const float* __restrict__ a_out,
                                                   float* __restrict__ pA0, float* __restrict__ pA1,
                                                   float* __restrict__ pB0, float* __restrict__ pB1,
                                                   int N) {
    int idx = blockIdx.x * 256 + threadIdx.x;  // n*4 + h
    if (idx >= N * HEADS) return;
    int n = idx >> 2, hh = idx & 3;
    const float4* v4 = (const float4*)(hp + (size_t)n * DIM + hh * HD);
    const float4* ai = (const float4*)(a_in + hh * 2 * HD);
    const float4* ao = (const float4*)(a_out + hh * 2 * HD);
    float s0 = 0.f, s1 = 0.f, s2 = 0.f, s3 = 0.f;
#pragma unroll
    for (int i = 0; i < 8; ++i) {
        float4 v = v4[i];
        float4 x0 = ai[i], x1 = ai[8 + i], y0 = ao[i], y1 = ao[8 + i];
        s0 += v.x * x0.x + v.y * x0.y + v.z * x0.z + v.w * x0.w;
        s1 += v.x * x1.x + v.y * x1.y + v.z * x1.z + v.w * x1.w;
        s2 += v.x * y0.x + v.y * y0.y + v.z * y0.z + v.w * y0.w;
        s3 += v.x * y1.x + v.y * y1.y + v.z * y1.z + v.w * y1.w;
    }
    pA0[idx] = s0; pA1[idx] = s1; pB0[idx] = s2; pB1[idx] = s3;
}

// ---------------- CSR build ----------------
__global__ __launch_bounds__(256) void hist_k(const int* __restrict__ ei, int* __restrict__ deg,
                                              int E, int N) {
    int e = blockIdx.x * 256 + threadIdx.x;
    if (e >= E) return;
    int s = ei[e], d = ei[E + e];
    atomicAdd(&deg[d], 1);       // in-direction segment = receiver d
    atomicAdd(&deg[N + s], 1);   // out-direction segment = receiver s
}

__global__ __launch_bounds__(256) void scan1_k(const int* __restrict__ deg, int* __restrict__ off,
                                               int* __restrict__ bs, int M) {
    __shared__ int ls[256];
    int t = threadIdx.x;
    int i = blockIdx.x * 256 + t;
    int v = (i < M) ? deg[i] : 0;
    ls[t] = v;
    __syncthreads();
#pragma unroll
    for (int d = 1; d < 256; d <<= 1) {
        int u = (t >= d) ? ls[t - d] : 0;
        __syncthreads();
        ls[t] += u;
        __syncthreads();
    }
    if (i < M) off[i + 1] = ls[t];
    if (t == 255) bs[blockIdx.x] = ls[255];
}

__global__ __launch_bounds__(256) void scan2_k(const int* __restrict__ bs, int* __restrict__ bo, int B) {
    __shared__ int ls[256];
    int t = threadIdx.x;
    int per = (B + 255) / 256;
    int b0 = t * per, b1 = min(b0 + per, B);
    int sum = 0;
    for (int j = b0; j < b1; ++j) sum += bs[j];
    ls[t] = sum;
    __syncthreads();
#pragma unroll
    for (int d = 1; d < 256; d <<= 1) {
        int u = (t >= d) ? ls[t - d] : 0;
        __syncthreads();
        ls[t] += u;
        __syncthreads();
    }
    int base = (t == 0) ? 0 : ls[t - 1];
    for (int j = b0; j < b1; ++j) { bo[j] = base; base += bs[j]; }
}

__global__ __launch_bounds__(256) void scan3_k(int* __restrict__ off, const int* __restrict__ bo, int M) {
    int i = blockIdx.x * 256 + threadIdx.x;
    if (i < M) off[i + 1] += bo[blockIdx.x];
    if (i == 0) off[0] = 0;
}

__global__ __launch_bounds__(256) void scatter_k(const int* __restrict__ ei, int* __restrict__ cur,
                                                 int* __restrict__ csr, int E, int N) {
    int e = blockIdx.x * 256 + threadIdx.x;
    if (e >= E) return;
    int s = ei[e], d = ei[E + e];
    int p = atomicAdd(&cur[d], 1);
    csr[p] = s;                      // in-direction: store sender s at receiver d's segment
    int q = atomicAdd(&cur[N + s], 1);
    csr[q] = d;                      // out-direction: store sender d at receiver s's segment
}

// ---------------- fused: per-node softmax-aggregate (both dirs) + combine + LN ----------------
__global__ __launch_bounds__(256) void node_aggr_ln_k(const float* __restrict__ hp,
                                                      const float* __restrict__ h_self,
                                                      const float* __restrict__ pA0, const float* __restrict__ pA1,
                                                      const float* __restrict__ pB0, const float* __restrict__ pB1,
                                                      const int* __restrict__ off, const int* __restrict__ csr,
                                                      const float* __restrict__ bias,
                                                      const float* __restrict__ gamma,
                                                      const float* __restrict__ beta,
                                                      float* __restrict__ out, int N) {
    int wave = threadIdx.x >> 6;
    int lane = threadIdx.x & 63;
    int n = blockIdx.x * 4 + wave;
    if (n >= N) return;
    const int hsel = lane >> 5;  // 0 or 1: channel c0=lane has head hsel, c1=lane+64 has head 2+hsel

    float acc0 = 0.f, acc1 = 0.f;

#pragma unroll
    for (int dir = 0; dir < 2; ++dir) {
        const int seg = (dir == 0) ? n : N + n;
        const int beg = off[seg], end = off[seg + 1];
        if (beg == end) continue;
        const float* __restrict__ p0 = (dir == 0) ? pA0 : pB0;  // sender half
        const float* __restrict__ p1 = (dir == 0) ? pA1 : pB1;  // receiver half
        float4 r1 = ((const float4*)p1)[n];

        // pass 1: per-head max over edges (lane-strided)
        float m0 = -INFINITY, m1 = -INFINITY, m2 = -INFINITY, m3 = -INFINITY;
        for (int base = beg; base < end; base += 64) {
            int j = base + lane;
            if (j < end) {
                int sid = csr[j];
                float4 r0 = ((const float4*)p0)[sid];
                m0 = fmaxf(m0, lrelu(r0.x + r1.x));
                m1 = fmaxf(m1, lrelu(r0.y + r1.y));
                m2 = fmaxf(m2, lrelu(r0.z + r1.z));
                m3 = fmaxf(m3, lrelu(r0.w + r1.w));
            }
        }
#pragma unroll
        for (int d = 1; d < 64; d <<= 1) {
            m0 = fmaxf(m0, __shfl_xor(m0, d, 64));
            m1 = fmaxf(m1, __shfl_xor(m1, d, 64));
            m2 = fmaxf(m2, __shfl_xor(m2, d, 64));
            m3 = fmaxf(m3, __shfl_xor(m3, d, 64));
        }

        // pass 2: per-head sum of exp
        float s0 = 0.f, s1 = 0.f, s2 = 0.f, s3 = 0.f;
        for (int base = beg; base < end; base += 64) {
            int j = base + lane;
            if (j < end) {
                int sid = csr[j];
                float4 r0 = ((const float4*)p0)[sid];
                s0 += expf(lrelu(r0.x + r1.x) - m0);
                s1 += expf(lrelu(r0.y + r1.y) - m1);
                s2 += expf(lrelu(r0.z + r1.z) - m2);
                s3 += expf(lrelu(r0.w + r1.w) - m3);
            }
        }
#pragma unroll
        for (int d = 1; d < 64; d <<= 1) {
            s0 += __shfl_xor(s0, d, 64);
            s1 += __shfl_xor(s1, d, 64);
            s2 += __shfl_xor(s2, d, 64);
            s3 += __shfl_xor(s3, d, 64);
        }
        const float is0 = 1.f / (s0 + EPS_SM);
        const float is1 = 1.f / (s1 + EPS_SM);
        const float is2 = 1.f / (s2 + EPS_SM);
        const float is3 = 1.f / (s3 + EPS_SM);

        // pass 3: weighted gather-accumulate, 64-edge chunks, shfl broadcast
        for (int base = beg; base < end; base += 64) {
            int cnt = min(64, end - base);
            int sid = 0;
            float w0 = 0.f, w1 = 0.f, w2 = 0.f, w3 = 0.f;
            if (lane < cnt) {
                sid = csr[base + lane];
                float4 r0 = ((const float4*)p0)[sid];
                w0 = expf(lrelu(r0.x + r1.x) - m0) * is0;
                w1 = expf(lrelu(r0.y + r1.y) - m1) * is1;
                w2 = expf(lrelu(r0.z + r1.z) - m2) * is2;
                w3 = expf(lrelu(r0.w + r1.w) - m3) * is3;
            }
#pragma unroll 2
            for (int j = 0; j < cnt; ++j) {
                int sj = __shfl(sid, j, 64);
                float w0j = __shfl(w0, j, 64);
                float w1j = __shfl(w1, j, 64);
                float w2j = __shfl(w2, j, 64);
                float w3j = __shfl(w3, j, 64);
                float wa = (hsel == 0) ? w0j : w1j;
                float wb = (hsel == 0) ? w2j : w3j;
                const float* row = hp + (size_t)sj * DIM;
                acc0 += wa * row[lane];
                acc1 += wb * row[lane + 64];
            }
        }
    }

    // combine + LayerNorm
    size_t bb = (size_t)n * DIM;
    float x0 = h_self[bb + lane] + acc0 + bias[lane];
    float x1 = h_self[bb + lane + 64] + acc1 + bias[lane + 64];
    float sum = x0 + x1, sq = x0 * x0 + x1 * x1;
#pragma unroll
    for (int m = 1; m < 64; m <<= 1) {
        sum += __shfl_xor(sum, m, 64);
        sq += __shfl_xor(sq, m, 64);
    }
    float mean = sum * (1.f / 128.f);
    float var = sq * (1.f / 128.f) - mean * mean;
    float inv = rsqrtf(var + EPS_LN);
    out[bb + lane] = (x0 - mean) * inv * gamma[lane] + beta[lane];
    out[bb + lane + 64] = (x1 - mean) * inv * gamma[lane + 64] + beta[lane + 64];
}

extern "C" void kernel_launch(void* const* d_in, const int* in_sizes, int n_in,
                              void* d_out, int out_size, void* d_ws, size_t ws_size,
                              hipStream_t stream) {
    const float* h      = (const float*)d_in[0];
    const int*   ei     = (const int*)d_in[1];
    const float* W      = (const float*)d_in[2];
    const float* W_self = (const float*)d_in[3];
    const float* a_in   = (const float*)d_in[4];
    const float* a_out  = (const float*)d_in[5];
    const float* bias   = (const float*)d_in[6];
    const float* gamma  = (const float*)d_in[7];
    const float* beta   = (const float*)d_in[8];
    float* out = (float*)d_out;

    const int N = in_sizes[0] / DIM;
    const int E = in_sizes[1] / 2;
    const int M = 2 * N;                       // total segments (in + out)
    const int B = (M + 255) / 256;             // scan blocks

    // workspace layout
    float* ws = (float*)d_ws;
    size_t off_f = 0;
    float* h_proj = ws + off_f; off_f += (size_t)N * DIM;
    float* h_self = ws + off_f; off_f += (size_t)N * DIM;
    float* pA0 = ws + off_f; off_f += (size_t)N * 4;
    float* pA1 = ws + off_f; off_f += (size_t)N * 4;
    float* pB0 = ws + off_f; off_f += (size_t)N * 4;
    float* pB1 = ws + off_f; off_f += (size_t)N * 4;
    int* ip = (int*)(ws + off_f);
    size_t off_i = 0;
    int* deg = ip + off_i; off_i += M;
    int* off = ip + off_i; off_i += (size_t)M + 1;
    int* cur = ip + off_i; off_i += M;
    int* bs  = ip + off_i; off_i += B;
    int* bo  = ip + off_i; off_i += B;
    int* csr = ip + off_i; off_i += (size_t)2 * E;

    // ---- projections ----
    int gblocks = (N + 15) / 16;
    gemm_k<<<gblocks, 256, 0, stream>>>(h, W, h_proj, N);
    gemm_k<<<gblocks, 256, 0, stream>>>(h, W_self, h_self, N);
    node_dots_k<<<(N * 4 + 255) / 256, 256, 0, stream>>>(h_proj, a_in, a_out, pA0, pA1, pB0, pB1, N);

    // ---- CSR build ----
    hipMemsetAsync(deg, 0, (size_t)M * sizeof(int), stream);
    int eblocks = (E + 255) / 256;
    hist_k<<<eblocks, 256, 0, stream>>>(ei, deg, E, N);
    scan1_k<<<B, 256, 0, stream>>>(deg, off, bs, M);
    scan2_k<<<1, 256, 0, stream>>>(bs, bo, B);
    scan3_k<<<B, 256, 0, stream>>>(off, bo, M);
    hipMemcpyAsync(cur, off, (size_t)M * sizeof(int), hipMemcpyDeviceToDevice, stream);
    scatter_k<<<eblocks, 256, 0, stream>>>(ei, cur, csr, E, N);

    // ---- fused aggregate + LN ----
    node_aggr_ln_k<<<(N + 3) / 4, 256, 0, stream>>>(h_proj, h_self, pA0, pA1, pB0, pB1,
                                                    off, csr, bias, gamma, beta, out, N);
}

// Round 3
// 939.717 us; speedup vs baseline: 2.9533x; 1.0661x over previous
//
#include <hip/hip_runtime.h>
#include <math.h>

#define HEADS 4
#define HD 32
#define DIM 128
#define NEG_SLOPE 0.2f
#define EPS_SM 1e-8f
#define EPS_LN 1e-5f
#define GROWS 64

__device__ __forceinline__ float lrelu(float x) { return x > 0.f ? x : NEG_SLOPE * x; }
__device__ __forceinline__ unsigned bf16rne(float x) {
    unsigned b = __float_as_uint(x);
    return (b + 0x7fffu + ((b >> 16) & 1u)) >> 16;
}

// ---------------- fused dual GEMM: h@W -> outP, h@W_self -> outS ----------------
__global__ __launch_bounds__(256) void dual_gemm_k(const float* __restrict__ h,
                                                   const float* __restrict__ W,
                                                   const float* __restrict__ V,
                                                   float* __restrict__ outP,
                                                   float* __restrict__ outS, int N) {
    __shared__ float As[32][GROWS];   // k-major A chunk
    __shared__ float Ws[32][DIM];
    __shared__ float Vs[32][DIM];
    const int tid = threadIdx.x;
    const int cg = tid & 15;   // cols cg*8 .. cg*8+7
    const int rg = tid >> 4;   // rows rg*4 .. rg*4+3
    const int row0 = blockIdx.x * GROWS;

    float accP[4][8], accS[4][8];
#pragma unroll
    for (int r = 0; r < 4; ++r)
#pragma unroll
        for (int c = 0; c < 8; ++c) { accP[r][c] = 0.f; accS[r][c] = 0.f; }

    for (int kc = 0; kc < 4; ++kc) {
        __syncthreads();
        // stage A chunk (64 rows x 32 k), transposed to k-major
#pragma unroll
        for (int p = 0; p < 2; ++p) {
            int f = tid + p * 256;          // 0..511
            int r = f >> 3, c4 = f & 7;
            float4 v = make_float4(0.f, 0.f, 0.f, 0.f);
            if (row0 + r < N) v = ((const float4*)h)[(size_t)(row0 + r) * 32 + kc * 8 + c4];
            As[c4 * 4 + 0][r] = v.x;
            As[c4 * 4 + 1][r] = v.y;
            As[c4 * 4 + 2][r] = v.z;
            As[c4 * 4 + 3][r] = v.w;
        }
        // stage W, V chunks (32 k x 128 cols), already k-major
#pragma unroll
        for (int p = 0; p < 4; ++p) {
            int f = tid + p * 256;          // 0..1023
            int lk = f >> 5, c4 = f & 31;
            ((float4*)&Ws[lk][0])[c4] = ((const float4*)W)[(size_t)(kc * 32 + lk) * 32 + c4];
            ((float4*)&Vs[lk][0])[c4] = ((const float4*)V)[(size_t)(kc * 32 + lk) * 32 + c4];
        }
        __syncthreads();
#pragma unroll
        for (int kk = 0; kk < 32; ++kk) {
            float4 a = *(const float4*)&As[kk][rg * 4];
            float4 w0 = *(const float4*)&Ws[kk][cg * 8];
            float4 w1 = *(const float4*)&Ws[kk][cg * 8 + 4];
            float4 v0 = *(const float4*)&Vs[kk][cg * 8];
            float4 v1 = *(const float4*)&Vs[kk][cg * 8 + 4];
            float av[4] = {a.x, a.y, a.z, a.w};
            float wv[8] = {w0.x, w0.y, w0.z, w0.w, w1.x, w1.y, w1.z, w1.w};
            float vv[8] = {v0.x, v0.y, v0.z, v0.w, v1.x, v1.y, v1.z, v1.w};
#pragma unroll
            for (int r = 0; r < 4; ++r)
#pragma unroll
                for (int c = 0; c < 8; ++c) {
                    accP[r][c] += av[r] * wv[c];
                    accS[r][c] += av[r] * vv[c];
                }
        }
    }
#pragma unroll
    for (int r = 0; r < 4; ++r) {
        int row = row0 + rg * 4 + r;
        if (row < N) {
            float4 p0 = make_float4(accP[r][0], accP[r][1], accP[r][2], accP[r][3]);
            float4 p1 = make_float4(accP[r][4], accP[r][5], accP[r][6], accP[r][7]);
            float4 s0 = make_float4(accS[r][0], accS[r][1], accS[r][2], accS[r][3]);
            float4 s1 = make_float4(accS[r][4], accS[r][5], accS[r][6], accS[r][7]);
            ((float4*)outP)[(size_t)row * 32 + cg * 2] = p0;
            ((float4*)outP)[(size_t)row * 32 + cg * 2 + 1] = p1;
            ((float4*)outS)[(size_t)row * 32 + cg * 2] = s0;
            ((float4*)outS)[(size_t)row * 32 + cg * 2 + 1] = s1;
        }
    }
}

// ------------- pack h_proj channels (c, c+64) into one bf16x2 dword -------------
__global__ __launch_bounds__(256) void pack_k(const float* __restrict__ hp,
                                              unsigned* __restrict__ hp_pk, int N) {
    int idx = blockIdx.x * 256 + threadIdx.x;
    if (idx >= N * 64) return;
    int n = idx >> 6, c = idx & 63;
    float x0 = hp[(size_t)n * DIM + c];
    float x1 = hp[(size_t)n * DIM + c + 64];
    hp_pk[idx] = bf16rne(x0) | (bf16rne(x1) << 16);
}

// ------------- per-node per-head attention scalars (4 tables, N*4) -------------
__global__ __launch_bounds__(256) void node_dots_k(const float* __restrict__ hp,
                                                   const float* __restrict__ a_in,
                                                   const float* __restrict__ a_out,
                                                   float* __restrict__ pA0, float* __restrict__ pA1,
                                                   float* __restrict__ pB0, float* __restrict__ pB1,
                                                   int N) {
    int idx = blockIdx.x * 256 + threadIdx.x;  // n*4 + h
    if (idx >= N * HEADS) return;
    int n = idx >> 2, hh = idx & 3;
    const float4* v4 = (const float4*)(hp + (size_t)n * DIM + hh * HD);
    const float4* ai = (const float4*)(a_in + hh * 2 * HD);
    const float4* ao = (const float4*)(a_out + hh * 2 * HD);
    float s0 = 0.f, s1 = 0.f, s2 = 0.f, s3 = 0.f;
#pragma unroll
    for (int i = 0; i < 8; ++i) {
        float4 v = v4[i];
        float4 x0 = ai[i], x1 = ai[8 + i], y0 = ao[i], y1 = ao[8 + i];
        s0 += v.x * x0.x + v.y * x0.y + v.z * x0.z + v.w * x0.w;
        s1 += v.x * x1.x + v.y * x1.y + v.z * x1.z + v.w * x1.w;
        s2 += v.x * y0.x + v.y * y0.y + v.z * y0.z + v.w * y0.w;
        s3 += v.x * y1.x + v.y * y1.y + v.z * y1.z + v.w * y1.w;
    }
    pA0[idx] = s0; pA1[idx] = s1; pB0[idx] = s2; pB1[idx] = s3;
}

// ---------------- CSR build ----------------
__global__ __launch_bounds__(256) void hist_k(const int* __restrict__ ei, int* __restrict__ deg,
                                              int E, int N) {
    int e = blockIdx.x * 256 + threadIdx.x;
    if (e >= E) return;
    int s = ei[e], d = ei[E + e];
    atomicAdd(&deg[d], 1);
    atomicAdd(&deg[N + s], 1);
}

__global__ __launch_bounds__(256) void scan1_k(const int* __restrict__ deg, int* __restrict__ off,
                                               int* __restrict__ bs, int M) {
    __shared__ int ls[256];
    int t = threadIdx.x;
    int i = blockIdx.x * 256 + t;
    int v = (i < M) ? deg[i] : 0;
    ls[t] = v;
    __syncthreads();
#pragma unroll
    for (int d = 1; d < 256; d <<= 1) {
        int u = (t >= d) ? ls[t - d] : 0;
        __syncthreads();
        ls[t] += u;
        __syncthreads();
    }
    if (i < M) off[i + 1] = ls[t];
    if (t == 255) bs[blockIdx.x] = ls[255];
}

__global__ __launch_bounds__(256) void scan2_k(const int* __restrict__ bs, int* __restrict__ bo, int B) {
    __shared__ int ls[256];
    int t = threadIdx.x;
    int per = (B + 255) / 256;
    int b0 = t * per, b1 = min(b0 + per, B);
    int sum = 0;
    for (int j = b0; j < b1; ++j) sum += bs[j];
    ls[t] = sum;
    __syncthreads();
#pragma unroll
    for (int d = 1; d < 256; d <<= 1) {
        int u = (t >= d) ? ls[t - d] : 0;
        __syncthreads();
        ls[t] += u;
        __syncthreads();
    }
    int base = (t == 0) ? 0 : ls[t - 1];
    for (int j = b0; j < b1; ++j) { bo[j] = base; base += bs[j]; }
}

__global__ __launch_bounds__(256) void scan3_k(int* __restrict__ off, const int* __restrict__ bo, int M) {
    int i = blockIdx.x * 256 + threadIdx.x;
    if (i < M) off[i + 1] += bo[blockIdx.x];
    if (i == 0) off[0] = 0;
}

__global__ __launch_bounds__(256) void scatter_k(const int* __restrict__ ei, int* __restrict__ cur,
                                                 int* __restrict__ csr, int E, int N) {
    int e = blockIdx.x * 256 + threadIdx.x;
    if (e >= E) return;
    int s = ei[e], d = ei[E + e];
    int p = atomicAdd(&cur[d], 1);
    csr[p] = s;
    int q = atomicAdd(&cur[N + s], 1);
    csr[q] = d;
}

// ---------------- fused: per-node softmax-aggregate (both dirs) + combine + LN ----------------
__global__ __launch_bounds__(256) void node_aggr_ln_k(const unsigned* __restrict__ hp_pk,
                                                      const float* __restrict__ h_self,
                                                      const float* __restrict__ pA0, const float* __restrict__ pA1,
                                                      const float* __restrict__ pB0, const float* __restrict__ pB1,
                                                      const int* __restrict__ off, const int* __restrict__ csr,
                                                      const float* __restrict__ bias,
                                                      const float* __restrict__ gamma,
                                                      const float* __restrict__ beta,
                                                      float* __restrict__ out, int N) {
    int wave = threadIdx.x >> 6;
    int lane = threadIdx.x & 63;
    int n = blockIdx.x * 4 + wave;
    if (n >= N) return;
    const int hsel = lane >> 5;  // ch lane has head hsel; ch lane+64 has head 2+hsel

    float acc0 = 0.f, acc1 = 0.f;

#pragma unroll
    for (int dir = 0; dir < 2; ++dir) {
        const int seg = (dir == 0) ? n : N + n;
        const int beg = off[seg], end = off[seg + 1];
        const int len = end - beg;
        if (len == 0) continue;
        const float* __restrict__ p0 = (dir == 0) ? pA0 : pB0;  // sender half
        const float* __restrict__ p1 = (dir == 0) ? pA1 : pB1;  // receiver half
        float4 r1 = ((const float4*)p1)[n];

        if (len <= 64) {
            // ---- fast path: everything register-cached, single chunk ----
            int sid = 0;
            float e0 = -INFINITY, e1 = -INFINITY, e2 = -INFINITY, e3 = -INFINITY;
            if (lane < len) {
                sid = csr[beg + lane];
                float4 r0 = ((const float4*)p0)[sid];
                e0 = lrelu(r0.x + r1.x);
                e1 = lrelu(r0.y + r1.y);
                e2 = lrelu(r0.z + r1.z);
                e3 = lrelu(r0.w + r1.w);
            }
            float m0 = e0, m1 = e1, m2 = e2, m3 = e3;
#pragma unroll
            for (int d = 1; d < 64; d <<= 1) {
                m0 = fmaxf(m0, __shfl_xor(m0, d, 64));
                m1 = fmaxf(m1, __shfl_xor(m1, d, 64));
                m2 = fmaxf(m2, __shfl_xor(m2, d, 64));
                m3 = fmaxf(m3, __shfl_xor(m3, d, 64));
            }
            float w0 = 0.f, w1 = 0.f, w2 = 0.f, w3 = 0.f;
            if (lane < len) {
                w0 = expf(e0 - m0); w1 = expf(e1 - m1);
                w2 = expf(e2 - m2); w3 = expf(e3 - m3);
            }
            float s0 = w0, s1 = w1, s2 = w2, s3 = w3;
#pragma unroll
            for (int d = 1; d < 64; d <<= 1) {
                s0 += __shfl_xor(s0, d, 64);
                s1 += __shfl_xor(s1, d, 64);
                s2 += __shfl_xor(s2, d, 64);
                s3 += __shfl_xor(s3, d, 64);
            }
            w0 *= 1.f / (s0 + EPS_SM);
            w1 *= 1.f / (s1 + EPS_SM);
            w2 *= 1.f / (s2 + EPS_SM);
            w3 *= 1.f / (s3 + EPS_SM);

            if (len <= 32) {
                // lane-swap: lanes 32..63 carry (w1,w3) of lanes 0..31 -> 3 shfls/edge
                float t1 = __shfl_xor(w1, 32, 64);
                float t3 = __shfl_xor(w3, 32, 64);
                float uA = hsel ? t1 : w0;
                float uB = hsel ? t3 : w2;
                int src = (hsel << 5);
                for (int j = 0; j < len; ++j) {
                    int sj = __shfl(sid, j, 64);
                    float wa = __shfl(uA, j + src, 64);
                    float wb = __shfl(uB, j + src, 64);
                    unsigned pk = hp_pk[(size_t)sj * 64 + lane];
                    acc0 += wa * __uint_as_float(pk << 16);
                    acc1 += wb * __uint_as_float(pk & 0xffff0000u);
                }
            } else {
                for (int j = 0; j < len; ++j) {
                    int sj = __shfl(sid, j, 64);
                    float w0j = __shfl(w0, j, 64);
                    float w1j = __shfl(w1, j, 64);
                    float w2j = __shfl(w2, j, 64);
                    float w3j = __shfl(w3, j, 64);
                    float wa = hsel ? w1j : w0j;
                    float wb = hsel ? w3j : w2j;
                    unsigned pk = hp_pk[(size_t)sj * 64 + lane];
                    acc0 += wa * __uint_as_float(pk << 16);
                    acc1 += wb * __uint_as_float(pk & 0xffff0000u);
                }
            }
        } else {
            // ---- general path: 3-pass chunked (rare: deg > 64) ----
            float m0 = -INFINITY, m1 = -INFINITY, m2 = -INFINITY, m3 = -INFINITY;
            for (int base = beg; base < end; base += 64) {
                int j = base + lane;
                if (j < end) {
                    int sid = csr[j];
                    float4 r0 = ((const float4*)p0)[sid];
                    m0 = fmaxf(m0, lrelu(r0.x + r1.x));
                    m1 = fmaxf(m1, lrelu(r0.y + r1.y));
                    m2 = fmaxf(m2, lrelu(r0.z + r1.z));
                    m3 = fmaxf(m3, lrelu(r0.w + r1.w));
                }
            }
#pragma unroll
            for (int d = 1; d < 64; d <<= 1) {
                m0 = fmaxf(m0, __shfl_xor(m0, d, 64));
                m1 = fmaxf(m1, __shfl_xor(m1, d, 64));
                m2 = fmaxf(m2, __shfl_xor(m2, d, 64));
                m3 = fmaxf(m3, __shfl_xor(m3, d, 64));
            }
            float s0 = 0.f, s1 = 0.f, s2 = 0.f, s3 = 0.f;
            for (int base = beg; base < end; base += 64) {
                int j = base + lane;
                if (j < end) {
                    int sid = csr[j];
                    float4 r0 = ((const float4*)p0)[sid];
                    s0 += expf(lrelu(r0.x + r1.x) - m0);
                    s1 += expf(lrelu(r0.y + r1.y) - m1);
                    s2 += expf(lrelu(r0.z + r1.z) - m2);
                    s3 += expf(lrelu(r0.w + r1.w) - m3);
                }
            }
#pragma unroll
            for (int d = 1; d < 64; d <<= 1) {
                s0 += __shfl_xor(s0, d, 64);
                s1 += __shfl_xor(s1, d, 64);
                s2 += __shfl_xor(s2, d, 64);
                s3 += __shfl_xor(s3, d, 64);
            }
            const float is0 = 1.f / (s0 + EPS_SM);
            const float is1 = 1.f / (s1 + EPS_SM);
            const float is2 = 1.f / (s2 + EPS_SM);
            const float is3 = 1.f / (s3 + EPS_SM);
            for (int base = beg; base < end; base += 64) {
                int cnt = min(64, end - base);
                int sid = 0;
                float w0 = 0.f, w1 = 0.f, w2 = 0.f, w3 = 0.f;
                if (lane < cnt) {
                    sid = csr[base + lane];
                    float4 r0 = ((const float4*)p0)[sid];
                    w0 = expf(lrelu(r0.x + r1.x) - m0) * is0;
                    w1 = expf(lrelu(r0.y + r1.y) - m1) * is1;
                    w2 = expf(lrelu(r0.z + r1.z) - m2) * is2;
                    w3 = expf(lrelu(r0.w + r1.w) - m3) * is3;
                }
                for (int j = 0; j < cnt; ++j) {
                    int sj = __shfl(sid, j, 64);
                    float w0j = __shfl(w0, j, 64);
                    float w1j = __shfl(w1, j, 64);
                    float w2j = __shfl(w2, j, 64);
                    float w3j = __shfl(w3, j, 64);
                    float wa = hsel ? w1j : w0j;
                    float wb = hsel ? w3j : w2j;
                    unsigned pk = hp_pk[(size_t)sj * 64 + lane];
                    acc0 += wa * __uint_as_float(pk << 16);
                    acc1 += wb * __uint_as_float(pk & 0xffff0000u);
                }
            }
        }
    }

    // combine + LayerNorm
    size_t bb = (size_t)n * DIM;
    float x0 = h_self[bb + lane] + acc0 + bias[lane];
    float x1 = h_self[bb + lane + 64] + acc1 + bias[lane + 64];
    float sum = x0 + x1, sq = x0 * x0 + x1 * x1;
#pragma unroll
    for (int m = 1; m < 64; m <<= 1) {
        sum += __shfl_xor(sum, m, 64);
        sq += __shfl_xor(sq, m, 64);
    }
    float mean = sum * (1.f / 128.f);
    float var = sq * (1.f / 128.f) - mean * mean;
    float inv = rsqrtf(var + EPS_LN);
    out[bb + lane] = (x0 - mean) * inv * gamma[lane] + beta[lane];
    out[bb + lane + 64] = (x1 - mean) * inv * gamma[lane + 64] + beta[lane + 64];
}

extern "C" void kernel_launch(void* const* d_in, const int* in_sizes, int n_in,
                              void* d_out, int out_size, void* d_ws, size_t ws_size,
                              hipStream_t stream) {
    const float* h      = (const float*)d_in[0];
    const int*   ei     = (const int*)d_in[1];
    const float* W      = (const float*)d_in[2];
    const float* W_self = (const float*)d_in[3];
    const float* a_in   = (const float*)d_in[4];
    const float* a_out  = (const float*)d_in[5];
    const float* bias   = (const float*)d_in[6];
    const float* gamma  = (const float*)d_in[7];
    const float* beta   = (const float*)d_in[8];
    float* out = (float*)d_out;

    const int N = in_sizes[0] / DIM;
    const int E = in_sizes[1] / 2;
    const int M = 2 * N;
    const int B = (M + 255) / 256;

    // workspace layout
    float* ws = (float*)d_ws;
    size_t off_f = 0;
    float* h_proj = ws + off_f; off_f += (size_t)N * DIM;
    float* h_self = ws + off_f; off_f += (size_t)N * DIM;
    unsigned* hp_pk = (unsigned*)(ws + off_f); off_f += (size_t)N * 64;
    float* pA0 = ws + off_f; off_f += (size_t)N * 4;
    float* pA1 = ws + off_f; off_f += (size_t)N * 4;
    float* pB0 = ws + off_f; off_f += (size_t)N * 4;
    float* pB1 = ws + off_f; off_f += (size_t)N * 4;
    int* ip = (int*)(ws + off_f);
    size_t off_i = 0;
    int* deg = ip + off_i; off_i += M;
    int* off = ip + off_i; off_i += (size_t)M + 1;
    int* cur = ip + off_i; off_i += M;
    int* bs  = ip + off_i; off_i += B;
    int* bo  = ip + off_i; off_i += B;
    int* csr = ip + off_i; off_i += (size_t)2 * E;

    // ---- CSR build (independent of GEMM) ----
    hipMemsetAsync(deg, 0, (size_t)M * sizeof(int), stream);
    int eblocks = (E + 255) / 256;
    hist_k<<<eblocks, 256, 0, stream>>>(ei, deg, E, N);
    scan1_k<<<B, 256, 0, stream>>>(deg, off, bs, M);
    scan2_k<<<1, 256, 0, stream>>>(bs, bo, B);
    scan3_k<<<B, 256, 0, stream>>>(off, bo, M);
    hipMemcpyAsync(cur, off, (size_t)M * sizeof(int), hipMemcpyDeviceToDevice, stream);
    scatter_k<<<eblocks, 256, 0, stream>>>(ei, cur, csr, E, N);

    // ---- projections ----
    dual_gemm_k<<<(N + GROWS - 1) / GROWS, 256, 0, stream>>>(h, W, W_self, h_proj, h_self, N);
    node_dots_k<<<(N * 4 + 255) / 256, 256, 0, stream>>>(h_proj, a_in, a_out, pA0, pA1, pB0, pB1, N);
    pack_k<<<(N * 64 + 255) / 256, 256, 0, stream>>>(h_proj, hp_pk, N);

    // ---- fused aggregate + LN ----
    node_aggr_ln_k<<<(N + 3) / 4, 256, 0, stream>>>(hp_pk, h_self, pA0, pA1, pB0, pB1,
                                                    off, csr, bias, gamma, beta, out, N);
}